// Round 2
// baseline (570170.312 us; speedup 1.0000x reference)
//
#include <hip/hip_runtime.h>
#include <hip/hip_bf16.h>
#include <math.h>

#define D 512
#define H 512
#define G3 1536

typedef _Float16 half2v __attribute__((ext_vector_type(2)));

__device__ __forceinline__ float sigmoidf_(float x) {
    return __fdividef(1.0f, 1.0f + __expf(-x));
}
__device__ __forceinline__ float tanhf_(float x) {
    // 1 - 2/(1+e^{2x}) ; exact at +-inf, ~2ulp mid-range
    return 1.0f - 2.0f * __fdividef(1.0f, 1.0f + __expf(2.0f * x));
}
__device__ __forceinline__ unsigned int comp4(const uint4& v, int q) {
    return q == 0 ? v.x : q == 1 ? v.y : q == 2 ? v.z : v.w;
}
__device__ __forceinline__ float fdot2_(unsigned int wu, unsigned int hu, float acc) {
#if __has_builtin(__builtin_amdgcn_fdot2)
    return __builtin_amdgcn_fdot2(__builtin_bit_cast(half2v, wu),
                                  __builtin_bit_cast(half2v, hu), acc, false);
#else
    half2v w = __builtin_bit_cast(half2v, wu);
    half2v h = __builtin_bit_cast(half2v, hu);
    return acc + (float)w.x * (float)h.x + (float)w.y * (float)h.y;
#endif
}

// ---------------- degree / norm ----------------
__global__ void deg_init(float* deg, int N) {
    int i = blockIdx.x * blockDim.x + threadIdx.x;
    if (i < N) deg[i] = 2.0f;
}
__global__ void deg_count(const int* __restrict__ ei, float* deg, int E) {
    int e = blockIdx.x * blockDim.x + threadIdx.x;
    if (e < E) atomicAdd(&deg[ei[E + e]], 1.0f);
}
__global__ void deg_inv(const float* __restrict__ deg, float* dinv, int N) {
    int i = blockIdx.x * blockDim.x + threadIdx.x;
    if (i < N) dinv[i] = rsqrtf(deg[i]);
}

// ---------------- f32 tiled GEMM ----------------
template<bool NT, bool BIAS>
__global__ __launch_bounds__(256) void gemm64(
    const float* __restrict__ A, const float* __restrict__ B,
    const float* __restrict__ bias, float* __restrict__ C,
    int M, int N, int K)
{
    __shared__ float As[16][68];
    __shared__ float Bs[16][68];
    const int tid = threadIdx.x;
    const int tx = tid & 15, ty = tid >> 4;
    const int bm = blockIdx.y * 64, bn = blockIdx.x * 64;
    float acc[4][4] = {};
    for (int k0 = 0; k0 < K; k0 += 16) {
        #pragma unroll
        for (int l = 0; l < 4; ++l) {
            int idx = tid + l * 256;
            int m = idx >> 4, kk = idx & 15;
            As[kk][m] = A[(size_t)(bm + m) * K + (k0 + kk)];
            if (NT) {
                int n = idx >> 4, k2 = idx & 15;
                Bs[k2][n] = B[(size_t)(bn + n) * K + (k0 + k2)];
            } else {
                int k2 = idx >> 6, n = idx & 63;
                Bs[k2][n] = B[(size_t)(k0 + k2) * N + (bn + n)];
            }
        }
        __syncthreads();
        #pragma unroll
        for (int kk = 0; kk < 16; ++kk) {
            float4 av = *(const float4*)&As[kk][ty * 4];
            float4 bv = *(const float4*)&Bs[kk][tx * 4];
            float a[4] = {av.x, av.y, av.z, av.w};
            float b[4] = {bv.x, bv.y, bv.z, bv.w};
            #pragma unroll
            for (int i = 0; i < 4; ++i)
                #pragma unroll
                for (int j = 0; j < 4; ++j)
                    acc[i][j] = fmaf(a[i], b[j], acc[i][j]);
        }
        __syncthreads();
    }
    #pragma unroll
    for (int i = 0; i < 4; ++i)
        #pragma unroll
        for (int j = 0; j < 4; ++j) {
            float v = acc[i][j];
            if (BIAS) v += bias[bn + tx * 4 + j];
            C[(size_t)(bm + ty * 4 + i) * N + (bn + tx * 4 + j)] = v;
        }
}

// ---------------- GCN aggregation ----------------
__global__ void gcn_init(const float* __restrict__ xw, const float* __restrict__ dinv,
                         const float* __restrict__ bias, float* __restrict__ gcn, int N) {
    int n = blockIdx.x;
    int k = threadIdx.x;
    float di = dinv[n];
    gcn[(size_t)n * D + k] = bias[k] + 2.0f * di * di * xw[(size_t)n * D + k];
}
__global__ void scatter_edges(const int* __restrict__ ei, const float* __restrict__ xw,
                              const float* __restrict__ dinv, float* __restrict__ gcn, int E) {
    int e = blockIdx.x;
    int row = ei[e], col = ei[E + e];
    float norm = dinv[row] * dinv[col];
    int k = threadIdx.x;
    atomicAdd(&gcn[(size_t)col * D + k], norm * xw[(size_t)row * D + k]);
}

// ---------------- weight pack: w_hh f32 -> per-thread-permuted f16 pairs ----------------
// gru thread tid = (w<<6)|l, l=(cc<<3)|rr ; wave w owns rows [96w,96w+96)
// batch b (0..11): row r = 96w + 8b + rr ; chunk cc covers cols [64cc, 64cc+64)
// pair p (0..31): cols (64cc+2p, 64cc+2p+1) ; flat i = 32b+p ; g=i>>2,q=i&3
// storage (uint): wpk[((g*1024)+tid)*4 + q]  -> gru loads uint4 at [g*1024+tid]
__global__ void pack_weights(const float* __restrict__ w_hh, unsigned int* __restrict__ wpk) {
    int e = blockIdx.x * blockDim.x + threadIdx.x;   // 0..393215
    int tid = e & 1023, i = e >> 10;
    int w = tid >> 6, l = tid & 63, rr = l & 7, cc = l >> 3;
    int b = i >> 5, p = i & 31;
    int r = w * 96 + b * 8 + rr;
    int c0 = cc * 64 + 2 * p;
    half2v hp;
    hp.x = (_Float16)w_hh[(size_t)r * H + c0];
    hp.y = (_Float16)w_hh[(size_t)r * H + c0 + 1];
    wpk[((size_t)(i >> 2) * 1024 + tid) * 4 + (i & 3)] = __builtin_bit_cast(unsigned int, hp);
}

// ---------------- GRU: single workgroup, 1024 threads, register-resident W ----------------
__global__ __launch_bounds__(1024) void gru_kernel(
    const uint4* __restrict__ wpk,    // [96*1024] uint4
    const float* __restrict__ gi,     // [T][1536]
    const float* __restrict__ b_hh,   // [1536]
    const float* __restrict__ hidden, // [512]
    float* __restrict__ out, int T)
{
    const int tid = threadIdx.x;
    const int w = tid >> 6, l = tid & 63;
    const int rr = l & 7, cc = l >> 3;

    __shared__ __align__(16) unsigned int h16[8 * 36];  // packed f16 pairs, stride 36 (bank-clean, 16B-aligned rows)
    __shared__ float hf[H];                              // f32 hidden (recurrence kept in f32)
    __shared__ float dots[G3];

    // ---- load my 384 packed weight words (96 x uint4), register-resident ----
    uint4 wv[96];
    #pragma unroll
    for (int g = 0; g < 96; ++g) wv[g] = wpk[g * 1024 + tid];

    // ---- gate-phase constants (threads < 256 handle elements 2t, 2t+1) ----
    float bh_r0 = 0, bh_r1 = 0, bh_z0 = 0, bh_z1 = 0, bh_n0 = 0, bh_n1 = 0;
    if (tid < 256) {
        float2 a = *(const float2*)&b_hh[2 * tid];
        float2 b = *(const float2*)&b_hh[H + 2 * tid];
        float2 c = *(const float2*)&b_hh[2 * H + 2 * tid];
        bh_r0 = a.x; bh_r1 = a.y; bh_z0 = b.x; bh_z1 = b.y; bh_n0 = c.x; bh_n1 = c.y;
    }

    // ---- init h ----
    if (tid < H) hf[tid] = hidden[tid];
    __syncthreads();
    if (tid < 256) {
        half2v hp; hp.x = (_Float16)hf[2 * tid]; hp.y = (_Float16)hf[2 * tid + 1];
        h16[(tid >> 5) * 36 + (tid & 31)] = __builtin_bit_cast(unsigned int, hp);
    }

    // ---- gi prefetch for t=0 ----
    float gr0 = 0, gr1 = 0, gz0 = 0, gz1 = 0, gn0 = 0, gn1 = 0;
    if (tid < 256) {
        const float2* g2 = (const float2*)gi;
        float2 a = g2[tid], b = g2[256 + tid], c = g2[512 + tid];
        gr0 = a.x; gr1 = a.y; gz0 = b.x; gz1 = b.y; gn0 = c.x; gn1 = c.y;
    }
    __syncthreads();

    for (int t = 0; t < T; ++t) {
        // my h chunk: 32 packed pairs (cols 64cc..64cc+64)
        uint4 hv[8];
        #pragma unroll
        for (int k = 0; k < 8; ++k)
            hv[k] = *(const uint4*)&h16[cc * 36 + 4 * k];

        // 12 batches of 8 rows; lane group {rr, rr+8,..,rr+56} covers one row
        #pragma unroll
        for (int b = 0; b < 12; ++b) {
            float a0 = 0.f, a1 = 0.f;
            #pragma unroll
            for (int p = 0; p < 32; p += 2) {
                const int i0 = b * 32 + p, i1 = i0 + 1;
                a0 = fdot2_(comp4(wv[i0 >> 2], i0 & 3), comp4(hv[p >> 2], p & 3), a0);
                a1 = fdot2_(comp4(wv[i1 >> 2], i1 & 3), comp4(hv[(p + 1) >> 2], (p + 1) & 3), a1);
            }
            float s = a0 + a1;
            s += __shfl_xor(s, 8, 64);
            s += __shfl_xor(s, 16, 64);
            s += __shfl_xor(s, 32, 64);
            if (cc == 0) dots[w * 96 + b * 8 + rr] = s;
        }
        __syncthreads();

        // ---- gates on threads < 256 (2 elements each) ----
        if (tid < 256) {
            const int e0 = 2 * tid;
            float2 dr = *(const float2*)&dots[e0];
            float2 dz = *(const float2*)&dots[H + e0];
            float2 dn = *(const float2*)&dots[2 * H + e0];
            float2 ho = *(const float2*)&hf[e0];
            float r0 = sigmoidf_(gr0 + dr.x + bh_r0);
            float r1 = sigmoidf_(gr1 + dr.y + bh_r1);
            float z0 = sigmoidf_(gz0 + dz.x + bh_z0);
            float z1 = sigmoidf_(gz1 + dz.y + bh_z1);
            float n0 = tanhf_(gn0 + fmaf(r0, dn.x + bh_n0, 0.f));
            float n1 = tanhf_(gn1 + fmaf(r1, dn.y + bh_n1, 0.f));
            float h0 = n0 + z0 * (ho.x - n0);
            float h1 = n1 + z1 * (ho.y - n1);
            *(float2*)&hf[e0] = make_float2(h0, h1);
            half2v hp; hp.x = (_Float16)h0; hp.y = (_Float16)h1;
            h16[(tid >> 5) * 36 + (tid & 31)] = __builtin_bit_cast(unsigned int, hp);
            *(float2*)&out[(size_t)t * H + e0] = make_float2(h0, h1);
            if (t == T - 1)
                *(float2*)&out[(size_t)T * H + e0] = make_float2(h0, h1);
            // prefetch gi for t+1 (whole step to cover latency)
            if (t + 1 < T) {
                const float2* g2 = (const float2*)(gi + (size_t)(t + 1) * G3);
                float2 a = g2[tid], b = g2[256 + tid], c = g2[512 + tid];
                gr0 = a.x; gr1 = a.y; gz0 = b.x; gz1 = b.y; gn0 = c.x; gn1 = c.y;
            }
        }
        __syncthreads();
    }
}

// ---------------- launcher ----------------
extern "C" void kernel_launch(void* const* d_in, const int* in_sizes, int n_in,
                              void* d_out, int out_size, void* d_ws, size_t ws_size,
                              hipStream_t stream) {
    const float* x      = (const float*)d_in[0];
    const int*   ei     = (const int*)d_in[1];
    const float* hidden = (const float*)d_in[2];
    const float* gw     = (const float*)d_in[3];
    const float* gb     = (const float*)d_in[4];
    const float* w_ih   = (const float*)d_in[5];
    const float* w_hh   = (const float*)d_in[6];
    const float* b_ih   = (const float*)d_in[7];
    const float* b_hh   = (const float*)d_in[8];
    float* out = (float*)d_out;

    const int N = in_sizes[0] / D;   // 16384
    const int E = in_sizes[1] / 2;   // 262144

    // ws layout (floats): deg[16k] dinv[16k] pad | gcn[N*D] | gi[N*3H]
    float* ws   = (float*)d_ws;
    float* deg  = ws;
    float* dinv = ws + 16384;
    float* gcn  = ws + 65536;
    float* gi   = gcn + (size_t)N * D;
    float* xw   = gi;                       // alias: xw dies before gi written
    unsigned int* wpk = (unsigned int*)gcn; // alias: gcn dies after gi GEMM

    deg_init<<<(N + 255) / 256, 256, 0, stream>>>(deg, N);
    deg_count<<<(E + 255) / 256, 256, 0, stream>>>(ei, deg, E);
    deg_inv<<<(N + 255) / 256, 256, 0, stream>>>(deg, dinv, N);

    gemm64<false, false><<<dim3(H / 64, N / 64), 256, 0, stream>>>(
        x, gw, nullptr, xw, N, H, D);

    gcn_init<<<N, 512, 0, stream>>>(xw, dinv, gb, gcn, N);
    scatter_edges<<<E, 512, 0, stream>>>(ei, xw, dinv, gcn, E);

    gemm64<true, true><<<dim3(G3 / 64, N / 64), 256, 0, stream>>>(
        gcn, w_ih, b_ih, gi, N, G3, H);

    // pack w_hh AFTER the gi GEMM (wpk aliases gcn region)
    pack_weights<<<1536, 256, 0, stream>>>(w_hh, wpk);

    gru_kernel<<<1, 1024, 0, stream>>>(
        (const uint4*)wpk, gi, b_hh, hidden, out, N);
}

// Round 3
// 40429.779 us; speedup vs baseline: 14.1027x; 14.1027x over previous
//
#include <hip/hip_runtime.h>
#include <hip/hip_bf16.h>
#include <math.h>

#define D 512
#define H 512
#define G3 1536
#define GRU_WGS 32
#define GRU_SLICE 16   // H / GRU_WGS
#define GRU_THREADS 512

__device__ __forceinline__ float sigmoidf_(float x) {
    return __fdividef(1.0f, 1.0f + __expf(-x));
}

// ---------------- degree / norm ----------------
__global__ void deg_init(float* deg, int N) {
    int i = blockIdx.x * blockDim.x + threadIdx.x;
    if (i < N) deg[i] = 2.0f;   // two self loops per node
}
__global__ void deg_count(const int* __restrict__ ei, float* deg, int E) {
    int e = blockIdx.x * blockDim.x + threadIdx.x;
    if (e < E) atomicAdd(&deg[ei[E + e]], 1.0f);
}
__global__ void deg_inv(const float* __restrict__ deg, float* dinv, int N) {
    int i = blockIdx.x * blockDim.x + threadIdx.x;
    if (i < N) dinv[i] = rsqrtf(deg[i]);
}

// ---------------- f32 tiled GEMM ----------------
template<bool NT, bool BIAS>
__global__ __launch_bounds__(256) void gemm64(
    const float* __restrict__ A, const float* __restrict__ B,
    const float* __restrict__ bias, float* __restrict__ C,
    int M, int N, int K)
{
    __shared__ float As[16][68];
    __shared__ float Bs[16][68];
    const int tid = threadIdx.x;
    const int tx = tid & 15, ty = tid >> 4;
    const int bm = blockIdx.y * 64, bn = blockIdx.x * 64;
    float acc[4][4] = {};
    for (int k0 = 0; k0 < K; k0 += 16) {
        #pragma unroll
        for (int l = 0; l < 4; ++l) {
            int idx = tid + l * 256;
            int m = idx >> 4, kk = idx & 15;
            As[kk][m] = A[(size_t)(bm + m) * K + (k0 + kk)];
            if (NT) {
                int n = idx >> 4, k2 = idx & 15;
                Bs[k2][n] = B[(size_t)(bn + n) * K + (k0 + k2)];
            } else {
                int k2 = idx >> 6, n = idx & 63;
                Bs[k2][n] = B[(size_t)(k0 + k2) * N + (bn + n)];
            }
        }
        __syncthreads();
        #pragma unroll
        for (int kk = 0; kk < 16; ++kk) {
            float4 av = *(const float4*)&As[kk][ty * 4];
            float4 bv = *(const float4*)&Bs[kk][tx * 4];
            float a[4] = {av.x, av.y, av.z, av.w};
            float b[4] = {bv.x, bv.y, bv.z, bv.w};
            #pragma unroll
            for (int i = 0; i < 4; ++i)
                #pragma unroll
                for (int j = 0; j < 4; ++j)
                    acc[i][j] = fmaf(a[i], b[j], acc[i][j]);
        }
        __syncthreads();
    }
    #pragma unroll
    for (int i = 0; i < 4; ++i)
        #pragma unroll
        for (int j = 0; j < 4; ++j) {
            float v = acc[i][j];
            if (BIAS) v += bias[bn + tx * 4 + j];
            C[(size_t)(bm + ty * 4 + i) * N + (bn + tx * 4 + j)] = v;
        }
}

// ---------------- GCN aggregation ----------------
__global__ void gcn_init(const float* __restrict__ xw, const float* __restrict__ dinv,
                         const float* __restrict__ bias, float* __restrict__ gcn, int N) {
    int n = blockIdx.x;
    int k = threadIdx.x;
    float di = dinv[n];
    gcn[(size_t)n * D + k] = bias[k] + 2.0f * di * di * xw[(size_t)n * D + k];
}
__global__ void scatter_edges(const int* __restrict__ ei, const float* __restrict__ xw,
                              const float* __restrict__ dinv, float* __restrict__ gcn, int E) {
    int e = blockIdx.x;
    int row = ei[e], col = ei[E + e];
    float norm = dinv[row] * dinv[col];
    int k = threadIdx.x;
    atomicAdd(&gcn[(size_t)col * D + k], norm * xw[(size_t)row * D + k]);
}

// ---------------- GRU ----------------
// h exchange: hx[2][512] of u64 words packing (tag<<32 | f32 bits).
// Tag == step index of the h value. Value+tag travel atomically in one
// relaxed agent-scope word -> no fences, no L2 wb/inv anywhere.
__global__ void gru_init(const float* __restrict__ hidden, unsigned long long* hx) {
    int i = threadIdx.x;           // 512 threads
    // slot 0 holds h_0 with tag 0 ; slot 1 poisoned with never-matching tag
    hx[i] = (unsigned long long)__float_as_uint(hidden[i]) & 0xffffffffull;  // tag 0
    hx[H + i] = 0xffffffff00000000ull;
}

// 32 persistent WGs x 512 threads. WG w owns h[16w..16w+16) and the 48
// corresponding rows of w_hh in registers (48 VGPR/thread, f32).
__global__ __launch_bounds__(GRU_THREADS, 1) void gru_kernel(
    const float* __restrict__ gi, const float* __restrict__ w_hh,
    const float* __restrict__ b_hh, unsigned long long* hx,
    float* __restrict__ out, int T)
{
    const int wg = blockIdx.x;
    const int tid = threadIdx.x;
    const int wave = tid >> 6;
    const int lane = tid & 63;

    __shared__ float h_lds[H];
    __shared__ float dots[48];

    // local rows lr = wave*6 + r ; lr<16 -> r-gate, <32 -> z-gate, else n-gate
    float w_reg[6][8];
    float bhh[6];
    #pragma unroll
    for (int r = 0; r < 6; ++r) {
        int lr = wave * 6 + r;
        int grow;
        if (lr < 16)      grow = wg * GRU_SLICE + lr;
        else if (lr < 32) grow = H + wg * GRU_SLICE + (lr - 16);
        else              grow = 2 * H + wg * GRU_SLICE + (lr - 32);
        bhh[r] = b_hh[grow];
        #pragma unroll
        for (int m = 0; m < 8; ++m)
            w_reg[r][m] = w_hh[(size_t)grow * H + lane + 64 * m];
    }

    // gi for t=0 (threads 0..15 hold the 3 gate inputs for their element)
    float gir = 0.f, giz = 0.f, gin = 0.f;
    if (tid < GRU_SLICE) {
        size_t base = (size_t)wg * GRU_SLICE + tid;
        gir = gi[base]; giz = gi[base + H]; gin = gi[base + 2 * H];
    }

    for (int t = 0; t < T; ++t) {
        // ---- consume h_t: poll my tagged word, no fence needed ----
        {
            unsigned long long* p = &hx[(t & 1) * H + tid];
            unsigned long long v = __hip_atomic_load(p, __ATOMIC_RELAXED,
                                                     __HIP_MEMORY_SCOPE_AGENT);
            while ((unsigned int)(v >> 32) != (unsigned int)t) {
                __builtin_amdgcn_s_sleep(1);
                v = __hip_atomic_load(p, __ATOMIC_RELAXED,
                                      __HIP_MEMORY_SCOPE_AGENT);
            }
            h_lds[tid] = __uint_as_float((unsigned int)v);
        }
        __syncthreads();

        // prefetch next step's gi (latency hidden under compute)
        float ngir = 0.f, ngiz = 0.f, ngin = 0.f;
        if (tid < GRU_SLICE && t + 1 < T) {
            size_t base = (size_t)(t + 1) * G3 + (size_t)wg * GRU_SLICE + tid;
            ngir = gi[base]; ngiz = gi[base + H]; ngin = gi[base + 2 * H];
        }

        float hr[8];
        #pragma unroll
        for (int m = 0; m < 8; ++m) hr[m] = h_lds[lane + 64 * m];

        #pragma unroll
        for (int r = 0; r < 6; ++r) {
            float s = 0.f;
            #pragma unroll
            for (int m = 0; m < 8; ++m) s = fmaf(w_reg[r][m], hr[m], s);
            #pragma unroll
            for (int off = 32; off > 0; off >>= 1)
                s += __shfl_xor(s, off, 64);
            if (lane == 0) dots[wave * 6 + r] = s + bhh[r];
        }
        __syncthreads();

        // ---- gates on threads < 16 ; publish tagged h_{t+1} ----
        if (tid < GRU_SLICE) {
            int j = wg * GRU_SLICE + tid;
            float hold = h_lds[j];
            float rg = sigmoidf_(gir + dots[tid]);
            float zg = sigmoidf_(giz + dots[16 + tid]);
            float ng = tanhf(gin + rg * dots[32 + tid]);
            float hn = ng + zg * (hold - ng);
            unsigned long long pv =
                ((unsigned long long)(unsigned int)(t + 1) << 32) |
                (unsigned long long)__float_as_uint(hn);
            __hip_atomic_store(&hx[((t + 1) & 1) * H + j], pv,
                               __ATOMIC_RELAXED, __HIP_MEMORY_SCOPE_AGENT);
            out[(size_t)t * H + j] = hn;
            if (t == T - 1) out[(size_t)T * H + j] = hn;   // h_last tail
        }
        gir = ngir; giz = ngiz; gin = ngin;
        // no barrier needed here: next-iter h_lds[tid] overwrite is gated by
        // the tag poll, which transitively orders after this WG's reads.
    }
}

// ---------------- launcher ----------------
extern "C" void kernel_launch(void* const* d_in, const int* in_sizes, int n_in,
                              void* d_out, int out_size, void* d_ws, size_t ws_size,
                              hipStream_t stream) {
    const float* x      = (const float*)d_in[0];
    const int*   ei     = (const int*)d_in[1];
    const float* hidden = (const float*)d_in[2];
    const float* gw     = (const float*)d_in[3];
    const float* gb     = (const float*)d_in[4];
    const float* w_ih   = (const float*)d_in[5];
    const float* w_hh   = (const float*)d_in[6];
    const float* b_ih   = (const float*)d_in[7];
    const float* b_hh   = (const float*)d_in[8];
    float* out = (float*)d_out;

    const int N = in_sizes[0] / D;   // 16384
    const int E = in_sizes[1] / 2;   // 262144

    // ws layout (floats): deg[16k] dinv[16k] hx[2048] | gcn[N*D] | gi[N*3H]
    float* ws   = (float*)d_ws;
    float* deg  = ws;
    float* dinv = ws + 16384;
    unsigned long long* hx = (unsigned long long*)(ws + 32768);
    float* gcn  = ws + 65536;
    float* gi   = gcn + (size_t)N * D;
    float* xw   = gi;   // alias: xw dies before gi is written

    deg_init<<<(N + 255) / 256, 256, 0, stream>>>(deg, N);
    deg_count<<<(E + 255) / 256, 256, 0, stream>>>(ei, deg, E);
    deg_inv<<<(N + 255) / 256, 256, 0, stream>>>(deg, dinv, N);

    gemm64<false, false><<<dim3(H / 64, N / 64), 256, 0, stream>>>(
        x, gw, nullptr, xw, N, H, D);

    gcn_init<<<N, 512, 0, stream>>>(xw, dinv, gb, gcn, N);
    scatter_edges<<<E, 512, 0, stream>>>(ei, xw, dinv, gcn, E);

    gemm64<true, true><<<dim3(G3 / 64, N / 64), 256, 0, stream>>>(
        gcn, w_ih, b_ih, gi, N, G3, H);

    gru_init<<<1, 512, 0, stream>>>(hidden, hx);
    gru_kernel<<<GRU_WGS, GRU_THREADS, 0, stream>>>(
        gi, w_hh, b_hh, hx, out, N);
}